// Round 2
// baseline (1158.156 us; speedup 1.0000x reference)
//
#include <hip/hip_runtime.h>

#define HH 64

static __global__ void k_set_ones(unsigned char* __restrict__ p, int n){
  int i = blockIdx.x * blockDim.x + threadIdx.x;
  if (i < n) p[i] = 1;
}

// Dense MLP evaluation: out[a,b,c] = sigmoid(MLP(p(c), p(b), p(a)))
// p(t) = (t*s + 0.5)/129 * 2 - 1  (x varies fastest = last index)
// Grid-stride persistent: weights staged to LDS once per block.
// __launch_bounds__(256,4): cap 128 VGPRs so h1[64] stays in VGPRs (48-VGPR
// default spilled h1 -> AGPR round-trips, 2.6x VALU instruction bloat).
static __global__ __launch_bounds__(256, 4) void k_eval_mlp(
    const float* __restrict__ w1, const float* __restrict__ b1,
    const float* __restrict__ w2, const float* __restrict__ b2,
    const float* __restrict__ w3, const float* __restrict__ b3,
    float* __restrict__ out, int R, int s)
{
  __shared__ float sw1[3*HH];
  __shared__ float sb1[HH];
  __shared__ float sw2t[HH*HH];   // sw2t[j*64+i] = w2[i*64+j]
  __shared__ float sb2[HH];
  __shared__ float sw3[HH];
  __shared__ float sb3s[1];
  const int t = threadIdx.x;
  // Conflict-free staging: consecutive lanes write consecutive LDS words.
  // (Global read is strided/uncoalesced but only 16 KB, L2-served.)
  for (int idx = t; idx < HH*HH; idx += 256){
    int j = idx >> 6, i = idx & 63;
    sw2t[idx] = w2[i*HH + j];
  }
  if (t < 3*HH) sw1[t] = w1[t];
  if (t < HH){ sb1[t] = b1[t]; sb2[t] = b2[t]; sw3[t] = w3[t]; }
  if (t == 0) sb3s[0] = b3[0];
  __syncthreads();

  const unsigned int n = (unsigned int)R * (unsigned int)R * (unsigned int)R;
  const float inv129x2 = 2.0f / 129.0f;
  for (unsigned int base = blockIdx.x * 256u; base < n; base += gridDim.x * 256u){
    unsigned int gid = base + (unsigned int)t;
    if (gid >= n) continue;
    const unsigned int c = gid % (unsigned int)R;
    const unsigned int r = gid / (unsigned int)R;
    const unsigned int b = r % (unsigned int)R;
    const unsigned int a = r / (unsigned int)R;
    const float x = ((float)(c * (unsigned int)s) + 0.5f) * inv129x2 - 1.0f;
    const float y = ((float)(b * (unsigned int)s) + 0.5f) * inv129x2 - 1.0f;
    const float z = ((float)(a * (unsigned int)s) + 0.5f) * inv129x2 - 1.0f;
    float h1[HH];
    #pragma unroll
    for (int i = 0; i < HH; ++i){
      float v = sb1[i];
      v = fmaf(x, sw1[i],        v);
      v = fmaf(y, sw1[HH + i],   v);
      v = fmaf(z, sw1[2*HH + i], v);
      h1[i] = fmaxf(v, 0.0f);
    }
    float o = sb3s[0];
    #pragma unroll 4
    for (int j = 0; j < HH; ++j){
      float acc = sb2[j];
      const float* wr = &sw2t[j*HH];
      #pragma unroll
      for (int i = 0; i < HH; ++i) acc = fmaf(h1[i], wr[i], acc);
      o = fmaf(fmaxf(acc, 0.0f), sw3[j], o);
    }
    out[gid] = 1.0f / (1.0f + expf(-o));
  }
}

// Per-level: trilinear upsample prev (Rp^3 -> R^3, coords exactly i/2),
// boundary-seed mask (interpolated binarization strictly in (0,1)),
// sign-mismatch mask, and the upsampled "calculated" mask.
static __global__ __launch_bounds__(256) void k_resize_boundary(
    const float* __restrict__ prev,            // Rp^3
    const float* __restrict__ occ_true,        // R^3
    const unsigned char* __restrict__ calc_prev, // Rp^3
    float* __restrict__ occ_i,                 // R^3
    unsigned char* __restrict__ bnd0,          // R^3
    unsigned char* __restrict__ mism,          // R^3
    unsigned char* __restrict__ calc_out,      // R^3
    int R, int Rp)
{
  const unsigned int n = (unsigned int)R * (unsigned int)R * (unsigned int)R;
  unsigned int gid = blockIdx.x * 256u + threadIdx.x;
  if (gid >= n) return;
  int c = (int)(gid % (unsigned int)R);
  unsigned int r = gid / (unsigned int)R;
  int b = (int)(r % (unsigned int)R);
  int a = (int)(r / (unsigned int)R);
  int a0 = a >> 1, da = a & 1;
  int b0i = b >> 1, db = b & 1;
  int c0 = c >> 1, dc = c & 1;
  float sum = 0.0f;
  int cnt = 0;
  const int tot = (da + 1) * (db + 1) * (dc + 1);
  for (int dz = 0; dz <= da; ++dz)
    for (int dy = 0; dy <= db; ++dy)
      for (int dx = 0; dx <= dc; ++dx){
        float v = prev[((unsigned int)(a0 + dz) * (unsigned int)Rp + (unsigned int)(b0i + dy)) * (unsigned int)Rp + (unsigned int)(c0 + dx)];
        sum += v;
        cnt += (v > 0.5f) ? 1 : 0;
      }
  float oi = sum / (float)tot;          // tot in {1,2,4,8}: exact
  occ_i[gid] = oi;
  bnd0[gid] = (cnt > 0 && cnt < tot) ? 1 : 0;
  mism[gid] = ((oi - 0.5f) * (occ_true[gid] - 0.5f) < 0.0f) ? 1 : 0;
  calc_out[gid] = ((da | db | dc) == 0)
      ? calc_prev[((unsigned int)a0 * (unsigned int)Rp + (unsigned int)b0i) * (unsigned int)Rp + (unsigned int)c0]
      : (unsigned char)0;
}

// nb = dilate3(src) & ~calc ; calc |= nb ; conf_out = nb & mism ; upd |= nb
static __global__ __launch_bounds__(256) void k_dilate_step(
    const unsigned char* __restrict__ src,
    const unsigned char* __restrict__ mism,
    unsigned char* __restrict__ calc,
    unsigned char* __restrict__ conf_out,
    unsigned char* __restrict__ upd,
    int R, int first)
{
  const unsigned int n = (unsigned int)R * (unsigned int)R * (unsigned int)R;
  unsigned int gid = blockIdx.x * 256u + threadIdx.x;
  if (gid >= n) return;
  int c = (int)(gid % (unsigned int)R);
  unsigned int r = gid / (unsigned int)R;
  int b = (int)(r % (unsigned int)R);
  int a = (int)(r / (unsigned int)R);
  int m = 0;
  for (int dz = -1; dz <= 1; ++dz){
    int az = a + dz; if (az < 0 || az >= R) continue;
    for (int dy = -1; dy <= 1; ++dy){
      int by = b + dy; if (by < 0 || by >= R) continue;
      for (int dx = -1; dx <= 1; ++dx){
        int cx = c + dx; if (cx < 0 || cx >= R) continue;
        m |= src[((unsigned int)az * (unsigned int)R + (unsigned int)by) * (unsigned int)R + (unsigned int)cx];
      }
    }
  }
  unsigned char nb = (m && !calc[gid]) ? (unsigned char)1 : (unsigned char)0;
  if (nb) calc[gid] = 1;
  conf_out[gid] = (nb && mism[gid]) ? (unsigned char)1 : (unsigned char)0;
  if (first) upd[gid] = nb;
  else if (nb) upd[gid] = 1;
}

static __global__ __launch_bounds__(256) void k_combine(
    const float* __restrict__ occ_true, const float* __restrict__ occ_i,
    const unsigned char* __restrict__ upd, float* __restrict__ out, unsigned int n)
{
  unsigned int gid = blockIdx.x * 256u + threadIdx.x;
  if (gid < n) out[gid] = upd[gid] ? occ_true[gid] : occ_i[gid];
}

extern "C" void kernel_launch(void* const* d_in, const int* in_sizes, int n_in,
                              void* d_out, int out_size, void* d_ws, size_t ws_size,
                              hipStream_t stream)
{
  const float* w1 = (const float*)d_in[0];
  const float* b1 = (const float*)d_in[1];
  const float* w2 = (const float*)d_in[2];
  const float* b2 = (const float*)d_in[3];
  const float* w3 = (const float*)d_in[4];
  const float* b3 = (const float*)d_in[5];
  float* out = (float*)d_out;

  const int NF = 129 * 129 * 129;  // 2146689
  const int NP = 65 * 65 * 65;     // 274625
  char* ws = (char*)d_ws;
  size_t off = 0;
  auto alloc = [&](size_t bytes) -> void* {
    void* p = (void*)(ws + off);
    off += (bytes + 255) & ~(size_t)255;
    return p;
  };
  float* f_true  = (float*)alloc((size_t)NF * 4);
  float* f_occi  = (float*)alloc((size_t)NF * 4);
  float* f_prevA = (float*)alloc((size_t)NP * 4);
  float* f_prevB = (float*)alloc((size_t)NP * 4);
  unsigned char* b_b0    = (unsigned char*)alloc(NF);
  unsigned char* b_mism  = (unsigned char*)alloc(NF);
  unsigned char* b_confA = (unsigned char*)alloc(NF);
  unsigned char* b_confB = (unsigned char*)alloc(NF);
  unsigned char* b_calcA = (unsigned char*)alloc(NF);
  unsigned char* b_calcB = (unsigned char*)alloc(NF);
  unsigned char* b_upd   = (unsigned char*)alloc(NF);
  (void)ws_size;

  const int MAXB = 2560;  // persistent-ish grid for eval kernel

  // Level 0: R=17 dense eval; calculated mask at 17^3 is all-true.
  {
    int R = 17, s = 8;
    int n = R * R * R;
    int blocks = (n + 255) / 256;
    k_eval_mlp<<<blocks, 256, 0, stream>>>(w1, b1, w2, b2, w3, b3, f_prevA, R, s);
    k_set_ones<<<blocks, 256, 0, stream>>>(b_calcA, n);
  }

  int Rp = 17;
  float* prev = f_prevA;
  unsigned char* calcP = b_calcA;
  unsigned char* calcC = b_calcB;
  for (int li = 1; li <= 3; ++li){
    int R = 2 * Rp - 1;
    int s = 128 / (R - 1);
    unsigned int n = (unsigned int)R * (unsigned int)R * (unsigned int)R;
    int blocks = (int)((n + 255u) / 256u);
    int eblocks = blocks < MAXB ? blocks : MAXB;
    float* occ_out = (li == 3) ? out : ((prev == f_prevA) ? f_prevB : f_prevA);

    k_eval_mlp<<<eblocks, 256, 0, stream>>>(w1, b1, w2, b2, w3, b3, f_true, R, s);
    k_resize_boundary<<<blocks, 256, 0, stream>>>(prev, f_true, calcP, f_occi, b_b0, b_mism, calcC, R, Rp);
    // boundary pass, then two conflict-propagation passes (N_CONFLICT_ITERS=2)
    k_dilate_step<<<blocks, 256, 0, stream>>>(b_b0,    b_mism, calcC, b_confA, b_upd, R, 1);
    k_dilate_step<<<blocks, 256, 0, stream>>>(b_confA, b_mism, calcC, b_confB, b_upd, R, 0);
    k_dilate_step<<<blocks, 256, 0, stream>>>(b_confB, b_mism, calcC, b_confA, b_upd, R, 0);
    k_combine<<<blocks, 256, 0, stream>>>(f_true, f_occi, b_upd, occ_out, n);

    prev = occ_out;
    unsigned char* tmpc = calcP; calcP = calcC; calcC = tmpc;
    Rp = R;
  }
  (void)in_sizes; (void)n_in; (void)out_size;
}

// Round 3
// 635.385 us; speedup vs baseline: 1.8228x; 1.8228x over previous
//
#include <hip/hip_runtime.h>

#define HH 64

static __global__ void k_set_ones(unsigned char* __restrict__ p, int n){
  int i = blockIdx.x * blockDim.x + threadIdx.x;
  if (i < n) p[i] = 1;
}

// Dense MLP evaluation, TWO LANES PER POINT.
// Lane pair {l, l^32} within a wave shares one point; each lane owns 32 of the
// 64 hidden units (h1 in 32 VGPRs), accumulates a 32-term partial per j, and
// combines via __shfl_xor(acc, 32). Live state ~48 VGPRs -> 64-VGPR bucket,
// 8 waves/SIMD, no AGPR round-trips, no scratch spill.
// (Round 1: 1 pt/thread needed ~85 VGPRs -> compiler chose 48 + AGPR spills,
//  2.6x VALU bloat. Round 2: launch_bounds(256,4) capped the UNIFIED VGPR+AGPR
//  file at 128 -> h1 spilled to scratch memory, 1.5 GB HBM traffic. Neither.)
static __global__ void k_eval_mlp(
    const float* __restrict__ w1, const float* __restrict__ b1,
    const float* __restrict__ w2, const float* __restrict__ b2,
    const float* __restrict__ w3, const float* __restrict__ b3,
    float* __restrict__ out, int R, int s)
{
  __shared__ float sw1[3*HH];
  __shared__ float sb1[HH];
  __shared__ float sw2t[HH*HH];   // sw2t[j*64+i] = w2[i*64+j]
  __shared__ float sb2[HH];
  __shared__ float sw3[HH];
  __shared__ float sb3s[1];
  const int t = threadIdx.x;
  // Conflict-free staging: consecutive lanes write consecutive LDS words.
  for (int idx = t; idx < HH*HH; idx += 256){
    int j = idx >> 6, i = idx & 63;
    sw2t[idx] = w2[i*HH + j];
  }
  if (t < 3*HH) sw1[t] = w1[t];
  if (t < HH){ sb1[t] = b1[t]; sb2[t] = b2[t]; sw3[t] = w3[t]; }
  if (t == 0) sb3s[0] = b3[0];
  __syncthreads();

  const unsigned int n = (unsigned int)R * (unsigned int)R * (unsigned int)R;
  const int lane = t & 63;
  const int half = lane >> 5;              // which 32 hidden units this lane owns
  const int ibase = half * 32;
  const unsigned int gwave = (blockIdx.x * 256u + (unsigned int)t) >> 6;
  const unsigned int pid = gwave * 32u + (unsigned int)(lane & 31);
  if (pid >= n) return;

  const unsigned int c = pid % (unsigned int)R;
  const unsigned int r = pid / (unsigned int)R;
  const unsigned int b = r % (unsigned int)R;
  const unsigned int a = r / (unsigned int)R;
  const float inv129x2 = 2.0f / 129.0f;
  const float x = ((float)(c * (unsigned int)s) + 0.5f) * inv129x2 - 1.0f;
  const float y = ((float)(b * (unsigned int)s) + 0.5f) * inv129x2 - 1.0f;
  const float z = ((float)(a * (unsigned int)s) + 0.5f) * inv129x2 - 1.0f;

  float h1[32];
  #pragma unroll
  for (int k = 0; k < 32; ++k){
    int i = ibase + k;
    float v = sb1[i];
    v = fmaf(x, sw1[i],        v);
    v = fmaf(y, sw1[HH + i],   v);
    v = fmaf(z, sw1[2*HH + i], v);
    h1[k] = fmaxf(v, 0.0f);
  }
  float o = sb3s[0];
  #pragma unroll 4
  for (int j = 0; j < HH; ++j){
    const float* wr = &sw2t[j*HH + ibase];
    float acc = 0.0f;
    #pragma unroll
    for (int k = 0; k < 32; ++k) acc = fmaf(h1[k], wr[k], acc);
    acc += __shfl_xor(acc, 32);            // combine the two half-dots
    o = fmaf(fmaxf(acc + sb2[j], 0.0f), sw3[j], o);
  }
  if (half == 0) out[pid] = 1.0f / (1.0f + expf(-o));
}

// Per-level: trilinear upsample prev (Rp^3 -> R^3, coords exactly i/2),
// boundary-seed mask (interpolated binarization strictly in (0,1)),
// sign-mismatch mask, and the upsampled "calculated" mask.
static __global__ __launch_bounds__(256) void k_resize_boundary(
    const float* __restrict__ prev,            // Rp^3
    const float* __restrict__ occ_true,        // R^3
    const unsigned char* __restrict__ calc_prev, // Rp^3
    float* __restrict__ occ_i,                 // R^3
    unsigned char* __restrict__ bnd0,          // R^3
    unsigned char* __restrict__ mism,          // R^3
    unsigned char* __restrict__ calc_out,      // R^3
    int R, int Rp)
{
  const unsigned int n = (unsigned int)R * (unsigned int)R * (unsigned int)R;
  unsigned int gid = blockIdx.x * 256u + threadIdx.x;
  if (gid >= n) return;
  int c = (int)(gid % (unsigned int)R);
  unsigned int r = gid / (unsigned int)R;
  int b = (int)(r % (unsigned int)R);
  int a = (int)(r / (unsigned int)R);
  int a0 = a >> 1, da = a & 1;
  int b0i = b >> 1, db = b & 1;
  int c0 = c >> 1, dc = c & 1;
  float sum = 0.0f;
  int cnt = 0;
  const int tot = (da + 1) * (db + 1) * (dc + 1);
  for (int dz = 0; dz <= da; ++dz)
    for (int dy = 0; dy <= db; ++dy)
      for (int dx = 0; dx <= dc; ++dx){
        float v = prev[((unsigned int)(a0 + dz) * (unsigned int)Rp + (unsigned int)(b0i + dy)) * (unsigned int)Rp + (unsigned int)(c0 + dx)];
        sum += v;
        cnt += (v > 0.5f) ? 1 : 0;
      }
  float oi = sum / (float)tot;          // tot in {1,2,4,8}: exact
  occ_i[gid] = oi;
  bnd0[gid] = (cnt > 0 && cnt < tot) ? 1 : 0;
  mism[gid] = ((oi - 0.5f) * (occ_true[gid] - 0.5f) < 0.0f) ? 1 : 0;
  calc_out[gid] = ((da | db | dc) == 0)
      ? calc_prev[((unsigned int)a0 * (unsigned int)Rp + (unsigned int)b0i) * (unsigned int)Rp + (unsigned int)c0]
      : (unsigned char)0;
}

// nb = dilate3(src) & ~calc ; calc |= nb ; conf_out = nb & mism ; upd |= nb
static __global__ __launch_bounds__(256) void k_dilate_step(
    const unsigned char* __restrict__ src,
    const unsigned char* __restrict__ mism,
    unsigned char* __restrict__ calc,
    unsigned char* __restrict__ conf_out,
    unsigned char* __restrict__ upd,
    int R, int first)
{
  const unsigned int n = (unsigned int)R * (unsigned int)R * (unsigned int)R;
  unsigned int gid = blockIdx.x * 256u + threadIdx.x;
  if (gid >= n) return;
  int c = (int)(gid % (unsigned int)R);
  unsigned int r = gid / (unsigned int)R;
  int b = (int)(r % (unsigned int)R);
  int a = (int)(r / (unsigned int)R);
  int m = 0;
  for (int dz = -1; dz <= 1; ++dz){
    int az = a + dz; if (az < 0 || az >= R) continue;
    for (int dy = -1; dy <= 1; ++dy){
      int by = b + dy; if (by < 0 || by >= R) continue;
      for (int dx = -1; dx <= 1; ++dx){
        int cx = c + dx; if (cx < 0 || cx >= R) continue;
        m |= src[((unsigned int)az * (unsigned int)R + (unsigned int)by) * (unsigned int)R + (unsigned int)cx];
      }
    }
  }
  unsigned char nb = (m && !calc[gid]) ? (unsigned char)1 : (unsigned char)0;
  if (nb) calc[gid] = 1;
  conf_out[gid] = (nb && mism[gid]) ? (unsigned char)1 : (unsigned char)0;
  if (first) upd[gid] = nb;
  else if (nb) upd[gid] = 1;
}

static __global__ __launch_bounds__(256) void k_combine(
    const float* __restrict__ occ_true, const float* __restrict__ occ_i,
    const unsigned char* __restrict__ upd, float* __restrict__ out, unsigned int n)
{
  unsigned int gid = blockIdx.x * 256u + threadIdx.x;
  if (gid < n) out[gid] = upd[gid] ? occ_true[gid] : occ_i[gid];
}

extern "C" void kernel_launch(void* const* d_in, const int* in_sizes, int n_in,
                              void* d_out, int out_size, void* d_ws, size_t ws_size,
                              hipStream_t stream)
{
  const float* w1 = (const float*)d_in[0];
  const float* b1 = (const float*)d_in[1];
  const float* w2 = (const float*)d_in[2];
  const float* b2 = (const float*)d_in[3];
  const float* w3 = (const float*)d_in[4];
  const float* b3 = (const float*)d_in[5];
  float* out = (float*)d_out;

  const int NF = 129 * 129 * 129;  // 2146689
  const int NP = 65 * 65 * 65;     // 274625
  char* ws = (char*)d_ws;
  size_t off = 0;
  auto alloc = [&](size_t bytes) -> void* {
    void* p = (void*)(ws + off);
    off += (bytes + 255) & ~(size_t)255;
    return p;
  };
  float* f_true  = (float*)alloc((size_t)NF * 4);
  float* f_occi  = (float*)alloc((size_t)NF * 4);
  float* f_prevA = (float*)alloc((size_t)NP * 4);
  float* f_prevB = (float*)alloc((size_t)NP * 4);
  unsigned char* b_b0    = (unsigned char*)alloc(NF);
  unsigned char* b_mism  = (unsigned char*)alloc(NF);
  unsigned char* b_confA = (unsigned char*)alloc(NF);
  unsigned char* b_confB = (unsigned char*)alloc(NF);
  unsigned char* b_calcA = (unsigned char*)alloc(NF);
  unsigned char* b_calcB = (unsigned char*)alloc(NF);
  unsigned char* b_upd   = (unsigned char*)alloc(NF);
  (void)ws_size;

  // eval kernel: 2 lanes per point -> 128 points per 256-thread block
  auto eval_blocks = [](int n){ return (n + 127) / 128; };

  // Level 0: R=17 dense eval; calculated mask at 17^3 is all-true.
  {
    int R = 17, s = 8;
    int n = R * R * R;
    k_eval_mlp<<<eval_blocks(n), 256, 0, stream>>>(w1, b1, w2, b2, w3, b3, f_prevA, R, s);
    k_set_ones<<<(n + 255) / 256, 256, 0, stream>>>(b_calcA, n);
  }

  int Rp = 17;
  float* prev = f_prevA;
  unsigned char* calcP = b_calcA;
  unsigned char* calcC = b_calcB;
  for (int li = 1; li <= 3; ++li){
    int R = 2 * Rp - 1;
    int s = 128 / (R - 1);
    unsigned int n = (unsigned int)R * (unsigned int)R * (unsigned int)R;
    int blocks = (int)((n + 255u) / 256u);
    float* occ_out = (li == 3) ? out : ((prev == f_prevA) ? f_prevB : f_prevA);

    k_eval_mlp<<<eval_blocks((int)n), 256, 0, stream>>>(w1, b1, w2, b2, w3, b3, f_true, R, s);
    k_resize_boundary<<<blocks, 256, 0, stream>>>(prev, f_true, calcP, f_occi, b_b0, b_mism, calcC, R, Rp);
    // boundary pass, then two conflict-propagation passes (N_CONFLICT_ITERS=2)
    k_dilate_step<<<blocks, 256, 0, stream>>>(b_b0,    b_mism, calcC, b_confA, b_upd, R, 1);
    k_dilate_step<<<blocks, 256, 0, stream>>>(b_confA, b_mism, calcC, b_confB, b_upd, R, 0);
    k_dilate_step<<<blocks, 256, 0, stream>>>(b_confB, b_mism, calcC, b_confA, b_upd, R, 0);
    k_combine<<<blocks, 256, 0, stream>>>(f_true, f_occi, b_upd, occ_out, n);

    prev = occ_out;
    unsigned char* tmpc = calcP; calcP = calcC; calcC = tmpc;
    Rp = R;
  }
  (void)in_sizes; (void)n_in; (void)out_size;
}

// Round 4
// 530.222 us; speedup vs baseline: 2.1843x; 1.1983x over previous
//
#include <hip/hip_runtime.h>

#define HH 64

static __global__ void k_set_ones(unsigned char* __restrict__ p, int n){
  int i = blockIdx.x * blockDim.x + threadIdx.x;
  if (i < n) p[i] = 1;
}

// ---------------- dense MLP eval (R=17, 33) — 2 lanes per point ----------------
static __global__ void k_eval_mlp(
    const float* __restrict__ w1, const float* __restrict__ b1,
    const float* __restrict__ w2, const float* __restrict__ b2,
    const float* __restrict__ w3, const float* __restrict__ b3,
    float* __restrict__ out, int R, int s)
{
  __shared__ float sw1[3*HH];
  __shared__ float sb1[HH];
  __shared__ float sw2t[HH*HH];   // sw2t[j*64+i] = w2[i*64+j]
  __shared__ float sb2[HH];
  __shared__ float sw3[HH];
  __shared__ float sb3s[1];
  const int t = threadIdx.x;
  for (int idx = t; idx < HH*HH; idx += 256){
    int j = idx >> 6, i = idx & 63;
    sw2t[idx] = w2[i*HH + j];
  }
  if (t < 3*HH) sw1[t] = w1[t];
  if (t < HH){ sb1[t] = b1[t]; sb2[t] = b2[t]; sw3[t] = w3[t]; }
  if (t == 0) sb3s[0] = b3[0];
  __syncthreads();

  const unsigned int n = (unsigned int)R * (unsigned int)R * (unsigned int)R;
  const int lane = t & 63;
  const int half = lane >> 5;
  const int ibase = half * 32;
  const unsigned int gwave = (blockIdx.x * 256u + (unsigned int)t) >> 6;
  const unsigned int pid = gwave * 32u + (unsigned int)(lane & 31);
  if (pid >= n) return;

  const unsigned int c = pid % (unsigned int)R;
  const unsigned int r = pid / (unsigned int)R;
  const unsigned int b = r % (unsigned int)R;
  const unsigned int a = r / (unsigned int)R;
  const float inv129x2 = 2.0f / 129.0f;
  const float x = ((float)(c * (unsigned int)s) + 0.5f) * inv129x2 - 1.0f;
  const float y = ((float)(b * (unsigned int)s) + 0.5f) * inv129x2 - 1.0f;
  const float z = ((float)(a * (unsigned int)s) + 0.5f) * inv129x2 - 1.0f;

  float h1[32];
  #pragma unroll
  for (int k = 0; k < 32; ++k){
    int i = ibase + k;
    float v = sb1[i];
    v = fmaf(x, sw1[i],        v);
    v = fmaf(y, sw1[HH + i],   v);
    v = fmaf(z, sw1[2*HH + i], v);
    h1[k] = fmaxf(v, 0.0f);
  }
  float o = sb3s[0];
  #pragma unroll 4
  for (int j = 0; j < HH; ++j){
    const float* wr = &sw2t[j*HH + ibase];
    float acc = 0.0f;
    #pragma unroll
    for (int k = 0; k < 32; ++k) acc = fmaf(h1[k], wr[k], acc);
    acc += __shfl_xor(acc, 32);
    o = fmaf(fmaxf(acc + sb2[j], 0.0f), sw3[j], o);
  }
  if (half == 0) out[pid] = 1.0f / (1.0f + expf(-o));
}

// ------------- sparse MLP eval over compacted index list (R=65, 129) -----------
// Writes f_true[pid] and mism[pid] only at candidate points; everything else
// in those arrays is dead (never consumed) — bit-exact vs dense evaluation.
static __global__ void k_eval_sparse(
    const float* __restrict__ w1, const float* __restrict__ b1,
    const float* __restrict__ w2, const float* __restrict__ b2,
    const float* __restrict__ w3, const float* __restrict__ b3,
    const int* __restrict__ idxl, const unsigned int* __restrict__ cnt,
    const float* __restrict__ occ_i,
    float* __restrict__ out, unsigned char* __restrict__ mism,
    int R, int s)
{
  if (blockIdx.x * 128u >= *cnt) return;   // block-uniform early exit
  __shared__ float sw1[3*HH];
  __shared__ float sb1[HH];
  __shared__ float sw2t[HH*HH];
  __shared__ float sb2[HH];
  __shared__ float sw3[HH];
  __shared__ float sb3s[1];
  const int t = threadIdx.x;
  for (int idx = t; idx < HH*HH; idx += 256){
    int j = idx >> 6, i = idx & 63;
    sw2t[idx] = w2[i*HH + j];
  }
  if (t < 3*HH) sw1[t] = w1[t];
  if (t < HH){ sb1[t] = b1[t]; sb2[t] = b2[t]; sw3[t] = w3[t]; }
  if (t == 0) sb3s[0] = b3[0];
  __syncthreads();

  const unsigned int count = *cnt;
  const int lane = t & 63;
  const int half = lane >> 5;
  const int ibase = half * 32;
  const unsigned int gwave = (blockIdx.x * 256u + (unsigned int)t) >> 6;
  const unsigned int slot = gwave * 32u + (unsigned int)(lane & 31);
  if (slot >= count) return;               // both lanes of a pair share slot
  const unsigned int pid = (unsigned int)idxl[slot];

  const unsigned int c = pid % (unsigned int)R;
  const unsigned int r = pid / (unsigned int)R;
  const unsigned int b = r % (unsigned int)R;
  const unsigned int a = r / (unsigned int)R;
  const float inv129x2 = 2.0f / 129.0f;
  const float x = ((float)(c * (unsigned int)s) + 0.5f) * inv129x2 - 1.0f;
  const float y = ((float)(b * (unsigned int)s) + 0.5f) * inv129x2 - 1.0f;
  const float z = ((float)(a * (unsigned int)s) + 0.5f) * inv129x2 - 1.0f;

  float h1[32];
  #pragma unroll
  for (int k = 0; k < 32; ++k){
    int i = ibase + k;
    float v = sb1[i];
    v = fmaf(x, sw1[i],        v);
    v = fmaf(y, sw1[HH + i],   v);
    v = fmaf(z, sw1[2*HH + i], v);
    h1[k] = fmaxf(v, 0.0f);
  }
  float o = sb3s[0];
  #pragma unroll 4
  for (int j = 0; j < HH; ++j){
    const float* wr = &sw2t[j*HH + ibase];
    float acc = 0.0f;
    #pragma unroll
    for (int k = 0; k < 32; ++k) acc = fmaf(h1[k], wr[k], acc);
    acc += __shfl_xor(acc, 32);
    o = fmaf(fmaxf(acc + sb2[j], 0.0f), sw3[j], o);
  }
  if (half == 0){
    float ot = 1.0f / (1.0f + expf(-o));
    out[pid] = ot;
    mism[pid] = ((occ_i[pid] - 0.5f) * (ot - 0.5f) < 0.0f) ? (unsigned char)1 : (unsigned char)0;
  }
}

// ---- upsample + seed + calc (no occ_true needed): for sparse levels ----
static __global__ __launch_bounds__(256) void k_resize_b0(
    const float* __restrict__ prev,              // Rp^3
    const unsigned char* __restrict__ calc_prev, // Rp^3
    float* __restrict__ occ_i,                   // R^3
    unsigned char* __restrict__ bnd0,            // R^3 seed
    unsigned char* __restrict__ calc_out,        // R^3
    int R, int Rp)
{
  const unsigned int n = (unsigned int)R * (unsigned int)R * (unsigned int)R;
  unsigned int gid = blockIdx.x * 256u + threadIdx.x;
  if (gid >= n) return;
  int c = (int)(gid % (unsigned int)R);
  unsigned int r = gid / (unsigned int)R;
  int b = (int)(r % (unsigned int)R);
  int a = (int)(r / (unsigned int)R);
  int a0 = a >> 1, da = a & 1;
  int b0i = b >> 1, db = b & 1;
  int c0 = c >> 1, dc = c & 1;
  float sum = 0.0f;
  int cnt = 0;
  const int tot = (da + 1) * (db + 1) * (dc + 1);
  for (int dz = 0; dz <= da; ++dz)
    for (int dy = 0; dy <= db; ++dy)
      for (int dx = 0; dx <= dc; ++dx){
        float v = prev[((unsigned int)(a0 + dz) * (unsigned int)Rp + (unsigned int)(b0i + dy)) * (unsigned int)Rp + (unsigned int)(c0 + dx)];
        sum += v;
        cnt += (v > 0.5f) ? 1 : 0;
      }
  occ_i[gid] = sum / (float)tot;
  bnd0[gid] = (cnt > 0 && cnt < tot) ? 1 : 0;
  calc_out[gid] = ((da | db | dc) == 0)
      ? calc_prev[((unsigned int)a0 * (unsigned int)Rp + (unsigned int)b0i) * (unsigned int)Rp + (unsigned int)c0]
      : (unsigned char)0;
}

// ---- dense variant with mism (for R=33 path; occ_true available first) ----
static __global__ __launch_bounds__(256) void k_resize_boundary(
    const float* __restrict__ prev, const float* __restrict__ occ_true,
    const unsigned char* __restrict__ calc_prev,
    float* __restrict__ occ_i, unsigned char* __restrict__ bnd0,
    unsigned char* __restrict__ mism, unsigned char* __restrict__ calc_out,
    int R, int Rp)
{
  const unsigned int n = (unsigned int)R * (unsigned int)R * (unsigned int)R;
  unsigned int gid = blockIdx.x * 256u + threadIdx.x;
  if (gid >= n) return;
  int c = (int)(gid % (unsigned int)R);
  unsigned int r = gid / (unsigned int)R;
  int b = (int)(r % (unsigned int)R);
  int a = (int)(r / (unsigned int)R);
  int a0 = a >> 1, da = a & 1;
  int b0i = b >> 1, db = b & 1;
  int c0 = c >> 1, dc = c & 1;
  float sum = 0.0f;
  int cnt = 0;
  const int tot = (da + 1) * (db + 1) * (dc + 1);
  for (int dz = 0; dz <= da; ++dz)
    for (int dy = 0; dy <= db; ++dy)
      for (int dx = 0; dx <= dc; ++dx){
        float v = prev[((unsigned int)(a0 + dz) * (unsigned int)Rp + (unsigned int)(b0i + dy)) * (unsigned int)Rp + (unsigned int)(c0 + dx)];
        sum += v;
        cnt += (v > 0.5f) ? 1 : 0;
      }
  float oi = sum / (float)tot;
  occ_i[gid] = oi;
  bnd0[gid] = (cnt > 0 && cnt < tot) ? 1 : 0;
  mism[gid] = ((oi - 0.5f) * (occ_true[gid] - 0.5f) < 0.0f) ? 1 : 0;
  calc_out[gid] = ((da | db | dc) == 0)
      ? calc_prev[((unsigned int)a0 * (unsigned int)Rp + (unsigned int)b0i) * (unsigned int)Rp + (unsigned int)c0]
      : (unsigned char)0;
}

// ---- zero conf/upd/counter (16B vector stores; arrays padded to 256) ----
static __global__ void k_zero3(unsigned char* __restrict__ a, unsigned char* __restrict__ b,
                               unsigned char* __restrict__ c, unsigned int* __restrict__ cnt,
                               unsigned int nwords)
{
  unsigned int i = blockIdx.x * 256u + threadIdx.x;
  if (i == 0) *cnt = 0u;
  if (i < nwords){
    uint4 z = make_uint4(0u,0u,0u,0u);
    ((uint4*)a)[i] = z;
    ((uint4*)b)[i] = z;
    ((uint4*)c)[i] = z;
  }
}

// ---- separable 7-wide (radius-3) box dilation along one axis ----
static __global__ __launch_bounds__(256) void k_dil7(
    const unsigned char* __restrict__ in, unsigned char* __restrict__ outp,
    int R, int axis)
{
  const unsigned int n = (unsigned int)R * (unsigned int)R * (unsigned int)R;
  unsigned int gid = blockIdx.x * 256u + threadIdx.x;
  if (gid >= n) return;
  int c = (int)(gid % (unsigned int)R);
  unsigned int r = gid / (unsigned int)R;
  int b = (int)(r % (unsigned int)R);
  int a = (int)(r / (unsigned int)R);
  int coord = (axis == 0) ? c : ((axis == 1) ? b : a);
  int stride = (axis == 0) ? 1 : ((axis == 1) ? R : R * R);
  int g = (int)gid;
  int m = 0;
  #pragma unroll
  for (int d = -3; d <= 3; ++d){
    int q = coord + d;
    if (q >= 0 && q < R) m |= in[g + d * stride];
  }
  outp[gid] = (unsigned char)(m ? 1 : 0);
}

// ---- ballot compaction of candidate mask -> index list ----
static __global__ __launch_bounds__(256) void k_compact(
    const unsigned char* __restrict__ cand, int* __restrict__ idxl,
    unsigned int* __restrict__ cnt, unsigned int n)
{
  unsigned int gid = blockIdx.x * 256u + threadIdx.x;
  bool pred = (gid < n) && (cand[gid] != 0);
  unsigned long long mask = __ballot(pred);
  int lane = (int)(threadIdx.x & 63u);
  unsigned int base = 0u;
  int tot = __popcll(mask);
  if (lane == 0 && tot) base = atomicAdd(cnt, (unsigned int)tot);
  base = (unsigned int)__shfl((int)base, 0);
  if (pred){
    int pre = __popcll(mask & ((1ull << lane) - 1ull));
    idxl[base + (unsigned int)pre] = (int)gid;
  }
}

// ---- sparse dilate-step over candidate list (conf arrays pre-zeroed) ----
static __global__ __launch_bounds__(256) void k_dilate_sparse(
    const int* __restrict__ idxl, const unsigned int* __restrict__ cnt,
    const unsigned char* __restrict__ src, const unsigned char* __restrict__ mism,
    unsigned char* __restrict__ calc, unsigned char* __restrict__ conf_out,
    unsigned char* __restrict__ upd, int R)
{
  const unsigned int count = *cnt;
  for (unsigned int slot = blockIdx.x * 256u + threadIdx.x; slot < count;
       slot += gridDim.x * 256u){
    int gid = idxl[slot];
    int c = gid % R;
    int r = gid / R;
    int b = r % R;
    int a = r / R;
    int m = 0;
    for (int dz = -1; dz <= 1; ++dz){
      int az = a + dz; if (az < 0 || az >= R) continue;
      for (int dy = -1; dy <= 1; ++dy){
        int by = b + dy; if (by < 0 || by >= R) continue;
        for (int dx = -1; dx <= 1; ++dx){
          int cx = c + dx; if (cx < 0 || cx >= R) continue;
          m |= src[(az * R + by) * R + cx];
        }
      }
    }
    unsigned char nb = (m && !calc[gid]) ? (unsigned char)1 : (unsigned char)0;
    conf_out[gid] = (nb && mism[gid]) ? (unsigned char)1 : (unsigned char)0;
    if (nb){ calc[gid] = 1; upd[gid] = 1; }
  }
}

// ---- dense dilate-step (R=33 path) ----
static __global__ __launch_bounds__(256) void k_dilate_step(
    const unsigned char* __restrict__ src, const unsigned char* __restrict__ mism,
    unsigned char* __restrict__ calc, unsigned char* __restrict__ conf_out,
    unsigned char* __restrict__ upd, int R, int first)
{
  const unsigned int n = (unsigned int)R * (unsigned int)R * (unsigned int)R;
  unsigned int gid = blockIdx.x * 256u + threadIdx.x;
  if (gid >= n) return;
  int c = (int)(gid % (unsigned int)R);
  unsigned int r = gid / (unsigned int)R;
  int b = (int)(r % (unsigned int)R);
  int a = (int)(r / (unsigned int)R);
  int m = 0;
  for (int dz = -1; dz <= 1; ++dz){
    int az = a + dz; if (az < 0 || az >= R) continue;
    for (int dy = -1; dy <= 1; ++dy){
      int by = b + dy; if (by < 0 || by >= R) continue;
      for (int dx = -1; dx <= 1; ++dx){
        int cx = c + dx; if (cx < 0 || cx >= R) continue;
        m |= src[((unsigned int)az * (unsigned int)R + (unsigned int)by) * (unsigned int)R + (unsigned int)cx];
      }
    }
  }
  unsigned char nb = (m && !calc[gid]) ? (unsigned char)1 : (unsigned char)0;
  if (nb) calc[gid] = 1;
  conf_out[gid] = (nb && mism[gid]) ? (unsigned char)1 : (unsigned char)0;
  if (first) upd[gid] = nb;
  else if (nb) upd[gid] = 1;
}

static __global__ __launch_bounds__(256) void k_combine(
    const float* __restrict__ occ_true, const float* __restrict__ occ_i,
    const unsigned char* __restrict__ upd, float* __restrict__ out, unsigned int n)
{
  unsigned int gid = blockIdx.x * 256u + threadIdx.x;
  if (gid < n) out[gid] = upd[gid] ? occ_true[gid] : occ_i[gid];
}

extern "C" void kernel_launch(void* const* d_in, const int* in_sizes, int n_in,
                              void* d_out, int out_size, void* d_ws, size_t ws_size,
                              hipStream_t stream)
{
  const float* w1 = (const float*)d_in[0];
  const float* b1 = (const float*)d_in[1];
  const float* w2 = (const float*)d_in[2];
  const float* b2 = (const float*)d_in[3];
  const float* w3 = (const float*)d_in[4];
  const float* b3 = (const float*)d_in[5];
  float* out = (float*)d_out;

  const int NF = 129 * 129 * 129;  // 2146689
  const int NP = 65 * 65 * 65;
  char* ws = (char*)d_ws;
  size_t off = 0;
  auto alloc = [&](size_t bytes) -> void* {
    void* p = (void*)(ws + off);
    off += (bytes + 255) & ~(size_t)255;
    return p;
  };
  float* f_true  = (float*)alloc((size_t)NF * 4);
  float* f_occi  = (float*)alloc((size_t)NF * 4);
  float* f_prevA = (float*)alloc((size_t)NP * 4);
  float* f_prevB = (float*)alloc((size_t)NP * 4);
  int*   i_idx   = (int*)alloc((size_t)NF * 4);
  unsigned int* u_cnt = (unsigned int*)alloc(256);
  unsigned char* b_b0    = (unsigned char*)alloc(NF);
  unsigned char* b_mism  = (unsigned char*)alloc(NF);
  unsigned char* b_confA = (unsigned char*)alloc(NF);
  unsigned char* b_confB = (unsigned char*)alloc(NF);
  unsigned char* b_calcA = (unsigned char*)alloc(NF);
  unsigned char* b_calcB = (unsigned char*)alloc(NF);
  unsigned char* b_upd   = (unsigned char*)alloc(NF);
  unsigned char* b_cand  = (unsigned char*)alloc(NF);
  unsigned char* b_tmp   = (unsigned char*)alloc(NF);
  (void)ws_size;

  auto eval_blocks = [](int n){ return (n + 127) / 128; };

  // Level 0: R=17 dense eval; calculated mask all-true.
  {
    int R = 17, s = 8;
    int n = R * R * R;
    k_eval_mlp<<<eval_blocks(n), 256, 0, stream>>>(w1, b1, w2, b2, w3, b3, f_prevA, R, s);
    k_set_ones<<<(n + 255) / 256, 256, 0, stream>>>(b_calcA, n);
  }

  int Rp = 17;
  float* prev = f_prevA;
  unsigned char* calcP = b_calcA;
  unsigned char* calcC = b_calcB;
  for (int li = 1; li <= 3; ++li){
    int R = 2 * Rp - 1;
    int s = 128 / (R - 1);
    unsigned int n = (unsigned int)R * (unsigned int)R * (unsigned int)R;
    int blocks = (int)((n + 255u) / 256u);
    float* occ_out = (li == 3) ? out : ((prev == f_prevA) ? f_prevB : f_prevA);

    if (R == 33){
      // dense path (small)
      k_eval_mlp<<<eval_blocks((int)n), 256, 0, stream>>>(w1, b1, w2, b2, w3, b3, f_true, R, s);
      k_resize_boundary<<<blocks, 256, 0, stream>>>(prev, f_true, calcP, f_occi, b_b0, b_mism, calcC, R, Rp);
      k_dilate_step<<<blocks, 256, 0, stream>>>(b_b0,    b_mism, calcC, b_confA, b_upd, R, 1);
      k_dilate_step<<<blocks, 256, 0, stream>>>(b_confA, b_mism, calcC, b_confB, b_upd, R, 0);
      k_dilate_step<<<blocks, 256, 0, stream>>>(b_confB, b_mism, calcC, b_confA, b_upd, R, 0);
      k_combine<<<blocks, 256, 0, stream>>>(f_true, f_occi, b_upd, occ_out, n);
    } else {
      // sparse path: eval only on C = dilate^3(seed)
      unsigned int nwords = (n + 15u) / 16u;
      int zblocks = (int)((nwords + 255u) / 256u);
      k_resize_b0<<<blocks, 256, 0, stream>>>(prev, calcP, f_occi, b_b0, calcC, R, Rp);
      k_zero3<<<zblocks, 256, 0, stream>>>(b_confA, b_confB, b_upd, u_cnt, nwords);
      k_dil7<<<blocks, 256, 0, stream>>>(b_b0,   b_cand, R, 0);
      k_dil7<<<blocks, 256, 0, stream>>>(b_cand, b_tmp,  R, 1);
      k_dil7<<<blocks, 256, 0, stream>>>(b_tmp,  b_cand, R, 2);
      k_compact<<<blocks, 256, 0, stream>>>(b_cand, i_idx, u_cnt, n);
      k_eval_sparse<<<eval_blocks((int)n), 256, 0, stream>>>(
          w1, b1, w2, b2, w3, b3, i_idx, u_cnt, f_occi, f_true, b_mism, R, s);
      int sblocks = blocks < 4096 ? blocks : 4096;
      k_dilate_sparse<<<sblocks, 256, 0, stream>>>(i_idx, u_cnt, b_b0,    b_mism, calcC, b_confA, b_upd, R);
      k_dilate_sparse<<<sblocks, 256, 0, stream>>>(i_idx, u_cnt, b_confA, b_mism, calcC, b_confB, b_upd, R);
      k_dilate_sparse<<<sblocks, 256, 0, stream>>>(i_idx, u_cnt, b_confB, b_mism, calcC, b_confA, b_upd, R);
      k_combine<<<blocks, 256, 0, stream>>>(f_true, f_occi, b_upd, occ_out, n);
    }

    prev = occ_out;
    unsigned char* tmpc = calcP; calcP = calcC; calcC = tmpc;
    Rp = R;
  }
  (void)in_sizes; (void)n_in; (void)out_size;
}

// Round 5
// 331.969 us; speedup vs baseline: 3.4887x; 1.5972x over previous
//
#include <hip/hip_runtime.h>

#define HH 64

static __global__ void k_set_ones(unsigned char* __restrict__ p, int n){
  int i = blockIdx.x * blockDim.x + threadIdx.x;
  if (i < n) p[i] = 1;
}

// ---------------- dense MLP eval (R=17, 33) — 2 lanes per point ----------------
static __global__ void k_eval_mlp(
    const float* __restrict__ w1, const float* __restrict__ b1,
    const float* __restrict__ w2, const float* __restrict__ b2,
    const float* __restrict__ w3, const float* __restrict__ b3,
    float* __restrict__ out, int R, int s)
{
  __shared__ float sw1[3*HH];
  __shared__ float sb1[HH];
  __shared__ float sw2t[HH*HH];   // sw2t[j*64+i] = w2[i*64+j]
  __shared__ float sb2[HH];
  __shared__ float sw3[HH];
  __shared__ float sb3s[1];
  const int t = threadIdx.x;
  for (int idx = t; idx < HH*HH; idx += 256){
    int j = idx >> 6, i = idx & 63;
    sw2t[idx] = w2[i*HH + j];
  }
  if (t < 3*HH) sw1[t] = w1[t];
  if (t < HH){ sb1[t] = b1[t]; sb2[t] = b2[t]; sw3[t] = w3[t]; }
  if (t == 0) sb3s[0] = b3[0];
  __syncthreads();

  const unsigned int n = (unsigned int)R * (unsigned int)R * (unsigned int)R;
  const int lane = t & 63;
  const int half = lane >> 5;
  const int ibase = half * 32;
  const unsigned int gwave = (blockIdx.x * 256u + (unsigned int)t) >> 6;
  const unsigned int pid = gwave * 32u + (unsigned int)(lane & 31);
  if (pid >= n) return;

  const unsigned int c = pid % (unsigned int)R;
  const unsigned int r = pid / (unsigned int)R;
  const unsigned int b = r % (unsigned int)R;
  const unsigned int a = r / (unsigned int)R;
  const float inv129x2 = 2.0f / 129.0f;
  const float x = ((float)(c * (unsigned int)s) + 0.5f) * inv129x2 - 1.0f;
  const float y = ((float)(b * (unsigned int)s) + 0.5f) * inv129x2 - 1.0f;
  const float z = ((float)(a * (unsigned int)s) + 0.5f) * inv129x2 - 1.0f;

  float h1[32];
  #pragma unroll
  for (int k = 0; k < 32; ++k){
    int i = ibase + k;
    float v = sb1[i];
    v = fmaf(x, sw1[i],        v);
    v = fmaf(y, sw1[HH + i],   v);
    v = fmaf(z, sw1[2*HH + i], v);
    h1[k] = fmaxf(v, 0.0f);
  }
  float o = sb3s[0];
  #pragma unroll 4
  for (int j = 0; j < HH; ++j){
    const float* wr = &sw2t[j*HH + ibase];
    float acc = 0.0f;
    #pragma unroll
    for (int k = 0; k < 32; ++k) acc = fmaf(h1[k], wr[k], acc);
    acc += __shfl_xor(acc, 32);
    o = fmaf(fmaxf(acc + sb2[j], 0.0f), sw3[j], o);
  }
  if (half == 0) out[pid] = 1.0f / (1.0f + expf(-o));
}

// ------------- sparse MLP eval over compacted index list (R=65, 129) -----------
static __global__ void k_eval_sparse(
    const float* __restrict__ w1, const float* __restrict__ b1,
    const float* __restrict__ w2, const float* __restrict__ b2,
    const float* __restrict__ w3, const float* __restrict__ b3,
    const int* __restrict__ idxl, const unsigned int* __restrict__ cnt,
    const float* __restrict__ occ_i,
    float* __restrict__ out, unsigned char* __restrict__ mism,
    int R, int s)
{
  if (blockIdx.x * 128u >= *cnt) return;   // block-uniform early exit
  __shared__ float sw1[3*HH];
  __shared__ float sb1[HH];
  __shared__ float sw2t[HH*HH];
  __shared__ float sb2[HH];
  __shared__ float sw3[HH];
  __shared__ float sb3s[1];
  const int t = threadIdx.x;
  for (int idx = t; idx < HH*HH; idx += 256){
    int j = idx >> 6, i = idx & 63;
    sw2t[idx] = w2[i*HH + j];
  }
  if (t < 3*HH) sw1[t] = w1[t];
  if (t < HH){ sb1[t] = b1[t]; sb2[t] = b2[t]; sw3[t] = w3[t]; }
  if (t == 0) sb3s[0] = b3[0];
  __syncthreads();

  const unsigned int count = *cnt;
  const int lane = t & 63;
  const int half = lane >> 5;
  const int ibase = half * 32;
  const unsigned int gwave = (blockIdx.x * 256u + (unsigned int)t) >> 6;
  const unsigned int slot = gwave * 32u + (unsigned int)(lane & 31);
  if (slot >= count) return;               // both lanes of a pair share slot
  const unsigned int pid = (unsigned int)idxl[slot];

  const unsigned int c = pid % (unsigned int)R;
  const unsigned int r = pid / (unsigned int)R;
  const unsigned int b = r % (unsigned int)R;
  const unsigned int a = r / (unsigned int)R;
  const float inv129x2 = 2.0f / 129.0f;
  const float x = ((float)(c * (unsigned int)s) + 0.5f) * inv129x2 - 1.0f;
  const float y = ((float)(b * (unsigned int)s) + 0.5f) * inv129x2 - 1.0f;
  const float z = ((float)(a * (unsigned int)s) + 0.5f) * inv129x2 - 1.0f;

  float h1[32];
  #pragma unroll
  for (int k = 0; k < 32; ++k){
    int i = ibase + k;
    float v = sb1[i];
    v = fmaf(x, sw1[i],        v);
    v = fmaf(y, sw1[HH + i],   v);
    v = fmaf(z, sw1[2*HH + i], v);
    h1[k] = fmaxf(v, 0.0f);
  }
  float o = sb3s[0];
  #pragma unroll 4
  for (int j = 0; j < HH; ++j){
    const float* wr = &sw2t[j*HH + ibase];
    float acc = 0.0f;
    #pragma unroll
    for (int k = 0; k < 32; ++k) acc = fmaf(h1[k], wr[k], acc);
    acc += __shfl_xor(acc, 32);
    o = fmaf(fmaxf(acc + sb2[j], 0.0f), sw3[j], o);
  }
  if (half == 0){
    float ot = 1.0f / (1.0f + expf(-o));
    out[pid] = ot;
    mism[pid] = ((occ_i[pid] - 0.5f) * (ot - 0.5f) < 0.0f) ? (unsigned char)1 : (unsigned char)0;
  }
}

// ---- upsample + seed + calc (no occ_true needed): for sparse levels ----
static __global__ __launch_bounds__(256) void k_resize_b0(
    const float* __restrict__ prev,              // Rp^3
    const unsigned char* __restrict__ calc_prev, // Rp^3
    float* __restrict__ occ_i,                   // R^3
    unsigned char* __restrict__ bnd0,            // R^3 seed
    unsigned char* __restrict__ calc_out,        // R^3
    int R, int Rp)
{
  const unsigned int n = (unsigned int)R * (unsigned int)R * (unsigned int)R;
  unsigned int gid = blockIdx.x * 256u + threadIdx.x;
  if (gid >= n) return;
  int c = (int)(gid % (unsigned int)R);
  unsigned int r = gid / (unsigned int)R;
  int b = (int)(r % (unsigned int)R);
  int a = (int)(r / (unsigned int)R);
  int a0 = a >> 1, da = a & 1;
  int b0i = b >> 1, db = b & 1;
  int c0 = c >> 1, dc = c & 1;
  float sum = 0.0f;
  int cnt = 0;
  const int tot = (da + 1) * (db + 1) * (dc + 1);
  for (int dz = 0; dz <= da; ++dz)
    for (int dy = 0; dy <= db; ++dy)
      for (int dx = 0; dx <= dc; ++dx){
        float v = prev[((unsigned int)(a0 + dz) * (unsigned int)Rp + (unsigned int)(b0i + dy)) * (unsigned int)Rp + (unsigned int)(c0 + dx)];
        sum += v;
        cnt += (v > 0.5f) ? 1 : 0;
      }
  occ_i[gid] = sum / (float)tot;
  bnd0[gid] = (cnt > 0 && cnt < tot) ? 1 : 0;
  calc_out[gid] = ((da | db | dc) == 0)
      ? calc_prev[((unsigned int)a0 * (unsigned int)Rp + (unsigned int)b0i) * (unsigned int)Rp + (unsigned int)c0]
      : (unsigned char)0;
}

// ---- dense variant with mism (for R=33 path; occ_true available first) ----
static __global__ __launch_bounds__(256) void k_resize_boundary(
    const float* __restrict__ prev, const float* __restrict__ occ_true,
    const unsigned char* __restrict__ calc_prev,
    float* __restrict__ occ_i, unsigned char* __restrict__ bnd0,
    unsigned char* __restrict__ mism, unsigned char* __restrict__ calc_out,
    int R, int Rp)
{
  const unsigned int n = (unsigned int)R * (unsigned int)R * (unsigned int)R;
  unsigned int gid = blockIdx.x * 256u + threadIdx.x;
  if (gid >= n) return;
  int c = (int)(gid % (unsigned int)R);
  unsigned int r = gid / (unsigned int)R;
  int b = (int)(r % (unsigned int)R);
  int a = (int)(r / (unsigned int)R);
  int a0 = a >> 1, da = a & 1;
  int b0i = b >> 1, db = b & 1;
  int c0 = c >> 1, dc = c & 1;
  float sum = 0.0f;
  int cnt = 0;
  const int tot = (da + 1) * (db + 1) * (dc + 1);
  for (int dz = 0; dz <= da; ++dz)
    for (int dy = 0; dy <= db; ++dy)
      for (int dx = 0; dx <= dc; ++dx){
        float v = prev[((unsigned int)(a0 + dz) * (unsigned int)Rp + (unsigned int)(b0i + dy)) * (unsigned int)Rp + (unsigned int)(c0 + dx)];
        sum += v;
        cnt += (v > 0.5f) ? 1 : 0;
      }
  float oi = sum / (float)tot;
  occ_i[gid] = oi;
  bnd0[gid] = (cnt > 0 && cnt < tot) ? 1 : 0;
  mism[gid] = ((oi - 0.5f) * (occ_true[gid] - 0.5f) < 0.0f) ? 1 : 0;
  calc_out[gid] = ((da | db | dc) == 0)
      ? calc_prev[((unsigned int)a0 * (unsigned int)Rp + (unsigned int)b0i) * (unsigned int)Rp + (unsigned int)c0]
      : (unsigned char)0;
}

// ---- zero conf/upd/counter (16B vector stores; arrays padded to 256) ----
static __global__ void k_zero3(unsigned char* __restrict__ a, unsigned char* __restrict__ b,
                               unsigned char* __restrict__ c, unsigned int* __restrict__ cnt,
                               unsigned int nwords)
{
  unsigned int i = blockIdx.x * 256u + threadIdx.x;
  if (i == 0) *cnt = 0u;
  if (i < nwords){
    uint4 z = make_uint4(0u,0u,0u,0u);
    ((uint4*)a)[i] = z;
    ((uint4*)b)[i] = z;
    ((uint4*)c)[i] = z;
  }
}

// ---- separable 7-wide (radius-3) box dilation along one axis ----
static __global__ __launch_bounds__(256) void k_dil7(
    const unsigned char* __restrict__ in, unsigned char* __restrict__ outp,
    int R, int axis)
{
  const unsigned int n = (unsigned int)R * (unsigned int)R * (unsigned int)R;
  unsigned int gid = blockIdx.x * 256u + threadIdx.x;
  if (gid >= n) return;
  int c = (int)(gid % (unsigned int)R);
  unsigned int r = gid / (unsigned int)R;
  int b = (int)(r % (unsigned int)R);
  int a = (int)(r / (unsigned int)R);
  int coord = (axis == 0) ? c : ((axis == 1) ? b : a);
  int stride = (axis == 0) ? 1 : ((axis == 1) ? R : R * R);
  int g = (int)gid;
  int m = 0;
  #pragma unroll
  for (int d = -3; d <= 3; ++d){
    int q = coord + d;
    if (q >= 0 && q < R) m |= in[g + d * stride];
  }
  outp[gid] = (unsigned char)(m ? 1 : 0);
}

// ---- deterministic prefix-sum compaction (replaces single-counter atomics:
//      33.5k same-address atomicAdds serialized at ~5ns each = 174 us) ----
static __global__ __launch_bounds__(256) void k_count(
    const unsigned char* __restrict__ cand, unsigned int* __restrict__ bcnt,
    unsigned int n)
{
  unsigned int gid = blockIdx.x * 256u + threadIdx.x;
  bool pred = (gid < n) && (cand[gid] != 0);
  unsigned long long m = __ballot(pred);
  __shared__ unsigned int wc[4];
  int wid = (int)(threadIdx.x >> 6);
  if ((threadIdx.x & 63u) == 0) wc[wid] = (unsigned int)__popcll(m);
  __syncthreads();
  if (threadIdx.x == 0) bcnt[blockIdx.x] = wc[0] + wc[1] + wc[2] + wc[3];
}

// single block, 1024 threads: exclusive scan of nb block counts (nb <= 8387)
static __global__ __launch_bounds__(1024) void k_scan(
    unsigned int* __restrict__ bcnt, unsigned int nb, unsigned int* __restrict__ total)
{
  __shared__ unsigned int part[1024];
  const unsigned int t = threadIdx.x;
  const unsigned int chunk = (nb + 1023u) / 1024u;
  const unsigned int beg = t * chunk;
  const unsigned int end = (beg + chunk < nb) ? (beg + chunk) : nb;
  unsigned int s = 0;
  for (unsigned int i = beg; i < end; ++i) s += bcnt[i];
  part[t] = s;
  __syncthreads();
  for (int offd = 1; offd < 1024; offd <<= 1){
    unsigned int v = (t >= (unsigned int)offd) ? part[t - offd] : 0u;
    __syncthreads();
    part[t] += v;
    __syncthreads();
  }
  unsigned int run = (t == 0) ? 0u : part[t - 1];
  for (unsigned int i = beg; i < end; ++i){
    unsigned int v = bcnt[i];
    bcnt[i] = run;
    run += v;
  }
  if (t == 1023) *total = part[1023];
}

static __global__ __launch_bounds__(256) void k_scatter(
    const unsigned char* __restrict__ cand, const unsigned int* __restrict__ boff,
    int* __restrict__ idxl, unsigned int n)
{
  unsigned int gid = blockIdx.x * 256u + threadIdx.x;
  bool pred = (gid < n) && (cand[gid] != 0);
  unsigned long long m = __ballot(pred);
  __shared__ unsigned int wbase[4];
  int wid = (int)(threadIdx.x >> 6);
  int lane = (int)(threadIdx.x & 63u);
  if (lane == 0) wbase[wid] = (unsigned int)__popcll(m);
  __syncthreads();
  if (threadIdx.x == 0){
    unsigned int b = boff[blockIdx.x];
    unsigned int t0 = wbase[0], t1 = wbase[1], t2 = wbase[2];
    wbase[0] = b; wbase[1] = b + t0; wbase[2] = b + t0 + t1; wbase[3] = b + t0 + t1 + t2;
  }
  __syncthreads();
  if (pred){
    int pre = __popcll(m & ((1ull << lane) - 1ull));
    idxl[wbase[wid] + (unsigned int)pre] = (int)gid;
  }
}

// ---- sparse dilate-step over candidate list (conf arrays pre-zeroed) ----
static __global__ __launch_bounds__(256) void k_dilate_sparse(
    const int* __restrict__ idxl, const unsigned int* __restrict__ cnt,
    const unsigned char* __restrict__ src, const unsigned char* __restrict__ mism,
    unsigned char* __restrict__ calc, unsigned char* __restrict__ conf_out,
    unsigned char* __restrict__ upd, int R)
{
  const unsigned int count = *cnt;
  for (unsigned int slot = blockIdx.x * 256u + threadIdx.x; slot < count;
       slot += gridDim.x * 256u){
    int gid = idxl[slot];
    int c = gid % R;
    int r = gid / R;
    int b = r % R;
    int a = r / R;
    int m = 0;
    for (int dz = -1; dz <= 1; ++dz){
      int az = a + dz; if (az < 0 || az >= R) continue;
      for (int dy = -1; dy <= 1; ++dy){
        int by = b + dy; if (by < 0 || by >= R) continue;
        for (int dx = -1; dx <= 1; ++dx){
          int cx = c + dx; if (cx < 0 || cx >= R) continue;
          m |= src[(az * R + by) * R + cx];
        }
      }
    }
    unsigned char nb = (m && !calc[gid]) ? (unsigned char)1 : (unsigned char)0;
    conf_out[gid] = (nb && mism[gid]) ? (unsigned char)1 : (unsigned char)0;
    if (nb){ calc[gid] = 1; upd[gid] = 1; }
  }
}

// ---- dense dilate-step (R=33 path) ----
static __global__ __launch_bounds__(256) void k_dilate_step(
    const unsigned char* __restrict__ src, const unsigned char* __restrict__ mism,
    unsigned char* __restrict__ calc, unsigned char* __restrict__ conf_out,
    unsigned char* __restrict__ upd, int R, int first)
{
  const unsigned int n = (unsigned int)R * (unsigned int)R * (unsigned int)R;
  unsigned int gid = blockIdx.x * 256u + threadIdx.x;
  if (gid >= n) return;
  int c = (int)(gid % (unsigned int)R);
  unsigned int r = gid / (unsigned int)R;
  int b = (int)(r % (unsigned int)R);
  int a = (int)(r / (unsigned int)R);
  int m = 0;
  for (int dz = -1; dz <= 1; ++dz){
    int az = a + dz; if (az < 0 || az >= R) continue;
    for (int dy = -1; dy <= 1; ++dy){
      int by = b + dy; if (by < 0 || by >= R) continue;
      for (int dx = -1; dx <= 1; ++dx){
        int cx = c + dx; if (cx < 0 || cx >= R) continue;
        m |= src[((unsigned int)az * (unsigned int)R + (unsigned int)by) * (unsigned int)R + (unsigned int)cx];
      }
    }
  }
  unsigned char nb = (m && !calc[gid]) ? (unsigned char)1 : (unsigned char)0;
  if (nb) calc[gid] = 1;
  conf_out[gid] = (nb && mism[gid]) ? (unsigned char)1 : (unsigned char)0;
  if (first) upd[gid] = nb;
  else if (nb) upd[gid] = 1;
}

static __global__ __launch_bounds__(256) void k_combine(
    const float* __restrict__ occ_true, const float* __restrict__ occ_i,
    const unsigned char* __restrict__ upd, float* __restrict__ out, unsigned int n)
{
  unsigned int gid = blockIdx.x * 256u + threadIdx.x;
  if (gid < n) out[gid] = upd[gid] ? occ_true[gid] : occ_i[gid];
}

extern "C" void kernel_launch(void* const* d_in, const int* in_sizes, int n_in,
                              void* d_out, int out_size, void* d_ws, size_t ws_size,
                              hipStream_t stream)
{
  const float* w1 = (const float*)d_in[0];
  const float* b1 = (const float*)d_in[1];
  const float* w2 = (const float*)d_in[2];
  const float* b2 = (const float*)d_in[3];
  const float* w3 = (const float*)d_in[4];
  const float* b3 = (const float*)d_in[5];
  float* out = (float*)d_out;

  const int NF = 129 * 129 * 129;  // 2146689
  const int NP = 65 * 65 * 65;
  char* ws = (char*)d_ws;
  size_t off = 0;
  auto alloc = [&](size_t bytes) -> void* {
    void* p = (void*)(ws + off);
    off += (bytes + 255) & ~(size_t)255;
    return p;
  };
  float* f_true  = (float*)alloc((size_t)NF * 4);
  float* f_occi  = (float*)alloc((size_t)NF * 4);
  float* f_prevA = (float*)alloc((size_t)NP * 4);
  float* f_prevB = (float*)alloc((size_t)NP * 4);
  int*   i_idx   = (int*)alloc((size_t)NF * 4);
  unsigned int* u_cnt  = (unsigned int*)alloc(256);
  unsigned int* u_bcnt = (unsigned int*)alloc(8448 * 4);
  unsigned char* b_b0    = (unsigned char*)alloc(NF);
  unsigned char* b_mism  = (unsigned char*)alloc(NF);
  unsigned char* b_confA = (unsigned char*)alloc(NF);
  unsigned char* b_confB = (unsigned char*)alloc(NF);
  unsigned char* b_calcA = (unsigned char*)alloc(NF);
  unsigned char* b_calcB = (unsigned char*)alloc(NF);
  unsigned char* b_upd   = (unsigned char*)alloc(NF);
  unsigned char* b_cand  = (unsigned char*)alloc(NF);
  unsigned char* b_tmp   = (unsigned char*)alloc(NF);
  (void)ws_size;

  auto eval_blocks = [](int n){ return (n + 127) / 128; };

  // Level 0: R=17 dense eval; calculated mask all-true.
  {
    int R = 17, s = 8;
    int n = R * R * R;
    k_eval_mlp<<<eval_blocks(n), 256, 0, stream>>>(w1, b1, w2, b2, w3, b3, f_prevA, R, s);
    k_set_ones<<<(n + 255) / 256, 256, 0, stream>>>(b_calcA, n);
  }

  int Rp = 17;
  float* prev = f_prevA;
  unsigned char* calcP = b_calcA;
  unsigned char* calcC = b_calcB;
  for (int li = 1; li <= 3; ++li){
    int R = 2 * Rp - 1;
    int s = 128 / (R - 1);
    unsigned int n = (unsigned int)R * (unsigned int)R * (unsigned int)R;
    int blocks = (int)((n + 255u) / 256u);
    float* occ_out = (li == 3) ? out : ((prev == f_prevA) ? f_prevB : f_prevA);

    if (R == 33){
      // dense path (small)
      k_eval_mlp<<<eval_blocks((int)n), 256, 0, stream>>>(w1, b1, w2, b2, w3, b3, f_true, R, s);
      k_resize_boundary<<<blocks, 256, 0, stream>>>(prev, f_true, calcP, f_occi, b_b0, b_mism, calcC, R, Rp);
      k_dilate_step<<<blocks, 256, 0, stream>>>(b_b0,    b_mism, calcC, b_confA, b_upd, R, 1);
      k_dilate_step<<<blocks, 256, 0, stream>>>(b_confA, b_mism, calcC, b_confB, b_upd, R, 0);
      k_dilate_step<<<blocks, 256, 0, stream>>>(b_confB, b_mism, calcC, b_confA, b_upd, R, 0);
      k_combine<<<blocks, 256, 0, stream>>>(f_true, f_occi, b_upd, occ_out, n);
    } else {
      // sparse path: eval only on C = dilate^3(seed)
      unsigned int nwords = (n + 15u) / 16u;
      int zblocks = (int)((nwords + 255u) / 256u);
      k_resize_b0<<<blocks, 256, 0, stream>>>(prev, calcP, f_occi, b_b0, calcC, R, Rp);
      k_zero3<<<zblocks, 256, 0, stream>>>(b_confA, b_confB, b_upd, u_cnt, nwords);
      k_dil7<<<blocks, 256, 0, stream>>>(b_b0,   b_cand, R, 0);
      k_dil7<<<blocks, 256, 0, stream>>>(b_cand, b_tmp,  R, 1);
      k_dil7<<<blocks, 256, 0, stream>>>(b_tmp,  b_cand, R, 2);
      // deterministic compaction: count -> scan -> scatter
      k_count<<<blocks, 256, 0, stream>>>(b_cand, u_bcnt, n);
      k_scan<<<1, 1024, 0, stream>>>(u_bcnt, (unsigned int)blocks, u_cnt);
      k_scatter<<<blocks, 256, 0, stream>>>(b_cand, u_bcnt, i_idx, n);
      k_eval_sparse<<<eval_blocks((int)n), 256, 0, stream>>>(
          w1, b1, w2, b2, w3, b3, i_idx, u_cnt, f_occi, f_true, b_mism, R, s);
      int sblocks = blocks < 4096 ? blocks : 4096;
      k_dilate_sparse<<<sblocks, 256, 0, stream>>>(i_idx, u_cnt, b_b0,    b_mism, calcC, b_confA, b_upd, R);
      k_dilate_sparse<<<sblocks, 256, 0, stream>>>(i_idx, u_cnt, b_confA, b_mism, calcC, b_confB, b_upd, R);
      k_dilate_sparse<<<sblocks, 256, 0, stream>>>(i_idx, u_cnt, b_confB, b_mism, calcC, b_confA, b_upd, R);
      k_combine<<<blocks, 256, 0, stream>>>(f_true, f_occi, b_upd, occ_out, n);
    }

    prev = occ_out;
    unsigned char* tmpc = calcP; calcP = calcC; calcC = tmpc;
    Rp = R;
  }
  (void)in_sizes; (void)n_in; (void)out_size;
}